// Round 13
// baseline (78.080 us; speedup 1.0000x reference)
//
#include <hip/hip_runtime.h>
#include <hip/hip_bf16.h>

typedef __attribute__((ext_vector_type(8))) short s8v;            // 8 x bf16
typedef __attribute__((ext_vector_type(4))) float f4v;            // 4 x f32

__device__ __forceinline__ short f2bf(float f) {
    __hip_bfloat16 h = __float2bfloat16(f);
    union { __hip_bfloat16 h; short s; } u{h};
    return u.s;
}
__device__ __forceinline__ float bf2f(unsigned short v) {
    union { unsigned u; float f; } x; x.u = ((unsigned)v) << 16; return x.f;
}
__device__ __forceinline__ unsigned packbf(float a, float b) {
    return (unsigned)(unsigned short)f2bf(a) | ((unsigned)(unsigned short)f2bf(b) << 16);
}

// ---------------------------------------------------------------------------
// prep: blocks [0,40) pack weights (W2' = g1 o W2) into MFMA fragment order;
// blocks 40/41 compute LN1-folding vectors s2 = colsum(bf16(W2')), bW2 = b1@W2;
// blocks [42,170) zero the winner array (device-side; hipMemsetAsync cost 40us).
// ---------------------------------------------------------------------------
__global__ void prep_kernel(const float* __restrict__ w1c, const float* __restrict__ w2c,
                            const float* __restrict__ g1c, const float* __restrict__ b1c,
                            const float* __restrict__ w1f, const float* __restrict__ w2f,
                            const float* __restrict__ g1f, const float* __restrict__ b1f,
                            short* __restrict__ p1c, short* __restrict__ p2c,
                            short* __restrict__ p1f, short* __restrict__ p2f,
                            float* __restrict__ s2c, float* __restrict__ bwc,
                            float* __restrict__ s2f, float* __restrict__ bwf,
                            int* __restrict__ win)
{
    int b = blockIdx.x, t = threadIdx.x;
    if (b >= 42) {                        // zero winner: 128 blocks x 256 thr x int4
        int idx4 = (b - 42) * 256 + t;
        int4 z; z.x = 0; z.y = 0; z.z = 0; z.w = 0;
        *(int4*)(win + idx4 * 4) = z;
        return;
    }
    if (b >= 40) {                        // folding vectors
        if (t >= 128) return;
        const float* W  = (b == 40) ? w2c : w2f;
        const float* g1 = (b == 40) ? g1c : g1f;
        const float* b1 = (b == 40) ? b1c : b1f;
        float* s2 = (b == 40) ? s2c : s2f;
        float* bw = (b == 40) ? bwc : bwf;
        float s = 0.f, w2sum = 0.f;
        for (int k = 0; k < 128; ++k) {
            float wv = W[k * 128 + t];
            s     += bf2f((unsigned short)f2bf(g1[k] * wv));  // match MFMA rounding
            w2sum += b1[k] * wv;
        }
        s2[t] = s; bw[t] = w2sum;
        return;
    }
    int id = b * 256 + t;                 // 40*256 = 160 frags * 64 lanes
    int f  = id >> 6, l = id & 63;
    const float* W; const float* g1 = nullptr; short* P; int fl;
    if      (f < 64)  { W = w1c; P = p1c; fl = f; }                   // K=256
    else if (f < 96)  { W = w2c; P = p2c; fl = f - 64;  g1 = g1c; }   // scaled
    else if (f < 128) { W = w1f; P = p1f; fl = f - 96; }
    else              { W = w2f; P = p2f; fl = f - 128; g1 = g1f; }   // scaled
    int g = l >> 4, c = l & 15;
    int ks = fl >> 3, n = fl & 7;
    s8v o;
    #pragma unroll
    for (int e = 0; e < 8; ++e) {
        int k = ks*32 + g*8 + e;
        float v = W[k * 128 + n*16 + c];
        if (g1) v *= g1[k];
        o[e] = f2bf(v);
    }
    *(s8v*)(P + ((fl*64 + l) << 3)) = o;
}

// ---------------------------------------------------------------------------
// Swapped-orientation fused MLP (lane owns one output row; lane-local LN + 2
// shuffle rounds; LN1 folded into W2'). Weights block-LDS-resident.
// R13: NT tiles per block, software-pipelined: per tile, cvt current X ->
// issue next tile's X/winner loads + current tile's gather BEFORE the MFMA
// phase, so every global load hides under a full tile of compute. Coarse
// holds W1(64KB)+W2'(32KB) both in LDS (96KB) - no mid-kernel re-stage.
// First nWinBlocks blocks do winner atomicMax resolution instead (i+1 enc).
// ---------------------------------------------------------------------------
template<int K1, bool FINE, int NT>
__global__ __launch_bounds__(512, 4)
void mlp_mfma(const float* __restrict__ X,
              const short* __restrict__ WpA,     // packed W1
              const short* __restrict__ WpB,     // packed W2' (g1-scaled)
              const float* __restrict__ s2v, const float* __restrict__ bwv,
              const float* __restrict__ g2v, const float* __restrict__ b2v,
              float* __restrict__ outF,            // FINE: f32 output
              unsigned short* __restrict__ outB,   // !FINE: bf16 fc output
              const int* __restrict__ winner,
              const unsigned short* __restrict__ fcB,
              const int* __restrict__ nr, const int* __restrict__ nc,
              int* __restrict__ win, int nWinBlocks)
{
    __shared__ short Ws[(K1 == 256) ? 49152 : 32768];   // 96KB coarse / 64KB fine
    constexpr int W2OFF = (K1 == 256) ? 32768 : 16384;
    constexpr int NCH1  = (K1/32) * 8 * 64;             // W1 16B chunks

    if (blockIdx.x < (unsigned)nWinBlocks) {
        int i = blockIdx.x * 512 + threadIdx.x;
        atomicMax(&win[nr[i] * 32 + nc[i]], i + 1);
        return;
    }
    const int bid  = blockIdx.x - nWinBlocks;
    const int tid  = threadIdx.x;
    const int wave = tid >> 6, lane = tid & 63;
    const int G = lane >> 4, n16 = lane & 15;
    const int row0 = bid * NT * 128 + wave * 16 + n16;

    // ---- stage W1 + W2' into LDS (coalesced 16B chunks) ----
    #pragma unroll
    for (int r = 0; r < NCH1/512; ++r) {
        int ch = r*512 + tid;
        *(s8v*)&Ws[ch*8] = *(const s8v*)(WpA + (size_t)ch*8);
    }
    #pragma unroll
    for (int r = 0; r < 4; ++r) {
        int ch = r*512 + tid;
        *(s8v*)&Ws[W2OFF + ch*8] = *(const s8v*)(WpB + (size_t)ch*8);
    }

    // ---- prologue: tile 0 first-half X + winner ----
    float4 aPf[4][2];
    {
        const float* pX0 = X + (size_t)row0 * K1 + G*8;
        #pragma unroll
        for (int k2 = 0; k2 < 4; ++k2) {
            aPf[k2][0] = *(const float4*)(pX0 + k2*32);
            aPf[k2][1] = *(const float4*)(pX0 + k2*32 + 4);
        }
    }
    int wv = 0;
    if constexpr (FINE) wv = winner[row0];

    __syncthreads();

    #pragma unroll
    for (int t = 0; t < NT; ++t) {
        const int row = row0 + t*128;

        // ---- cvt current first-half X to bf16 fragments ----
        s8v xf[4];
        #pragma unroll
        for (int k2 = 0; k2 < 4; ++k2) {
            s8v v;
            v[0] = f2bf(aPf[k2][0].x); v[1] = f2bf(aPf[k2][0].y);
            v[2] = f2bf(aPf[k2][0].z); v[3] = f2bf(aPf[k2][0].w);
            v[4] = f2bf(aPf[k2][1].x); v[5] = f2bf(aPf[k2][1].y);
            v[6] = f2bf(aPf[k2][1].z); v[7] = f2bf(aPf[k2][1].w);
            xf[k2] = v;
        }

        // ---- coarse: issue second-half X loads ----
        float4 bPf[4][2];
        if constexpr (K1 == 256) {
            const float* pX = X + (size_t)row * K1 + G*8;
            #pragma unroll
            for (int k2 = 0; k2 < 4; ++k2) {
                bPf[k2][0] = *(const float4*)(pX + (4+k2)*32);
                bPf[k2][1] = *(const float4*)(pX + (4+k2)*32 + 4);
            }
        }

        // ---- issue NEXT tile's X + winner (hidden under this tile's MFMA) ----
        int wv_next = 0;
        if (t + 1 < NT) {
            const float* pXn = X + (size_t)(row + 128) * K1 + G*8;
            #pragma unroll
            for (int k2 = 0; k2 < 4; ++k2) {
                aPf[k2][0] = *(const float4*)(pXn + k2*32);
                aPf[k2][1] = *(const float4*)(pXn + k2*32 + 4);
            }
            if constexpr (FINE) wv_next = winner[row + 128];
        }

        // ---- issue current tile's gather (winner known since last iter) ----
        ushort4 gv[8];
        bool hasw = false;
        if constexpr (FINE) {
            hasw = (wv > 0);
            const size_t src = (size_t)((wv - 1) & 32767) * 128;
            if (hasw) {
                #pragma unroll
                for (int mt = 0; mt < 8; ++mt)
                    gv[mt] = *(const ushort4*)(fcB + src + mt*16 + G*4);
            }
        }

        // ---------------- Layer 1: acc = W1^T @ X^T ----------------
        f4v acc[8];
        #pragma unroll
        for (int mt = 0; mt < 8; ++mt) acc[mt] = (f4v){0.f, 0.f, 0.f, 0.f};

        #pragma unroll
        for (int ks = 0; ks < 4; ++ks) {
            s8v wfr[8];
            #pragma unroll
            for (int mt = 0; mt < 8; ++mt)
                wfr[mt] = *(const s8v*)&Ws[((ks*8 + mt)*64 + lane) * 8];
            #pragma unroll
            for (int mt = 0; mt < 8; ++mt)
                acc[mt] = __builtin_amdgcn_mfma_f32_16x16x32_bf16(wfr[mt], xf[ks], acc[mt], 0, 0, 0);
        }
        if constexpr (K1 == 256) {
            #pragma unroll
            for (int k2 = 0; k2 < 4; ++k2) {
                s8v v;
                v[0] = f2bf(bPf[k2][0].x); v[1] = f2bf(bPf[k2][0].y);
                v[2] = f2bf(bPf[k2][0].z); v[3] = f2bf(bPf[k2][0].w);
                v[4] = f2bf(bPf[k2][1].x); v[5] = f2bf(bPf[k2][1].y);
                v[6] = f2bf(bPf[k2][1].z); v[7] = f2bf(bPf[k2][1].w);
                xf[k2] = v;
            }
            #pragma unroll
            for (int ks = 4; ks < 8; ++ks) {
                s8v wfr[8];
                #pragma unroll
                for (int mt = 0; mt < 8; ++mt)
                    wfr[mt] = *(const s8v*)&Ws[((ks*8 + mt)*64 + lane) * 8];
                #pragma unroll
                for (int mt = 0; mt < 8; ++mt)
                    acc[mt] = __builtin_amdgcn_mfma_f32_16x16x32_bf16(wfr[mt], xf[ks-4], acc[mt], 0, 0, 0);
            }
        }

        // ---------------- LN1 stats (lane-local + 2 shuffle rounds) ----------
        float sm = 0.f, sq = 0.f;
        #pragma unroll
        for (int mt = 0; mt < 8; ++mt)
            #pragma unroll
            for (int j = 0; j < 4; ++j) { float v = acc[mt][j]; sm += v; sq += v*v; }
        sm += __shfl_xor(sm, 16, 64); sm += __shfl_xor(sm, 32, 64);
        sq += __shfl_xor(sq, 16, 64); sq += __shfl_xor(sq, 32, 64);
        const float mean1 = sm * (1.f/128.f);
        const float rstd1 = rsqrtf(sq * (1.f/128.f) - mean1*mean1 + 1e-5f);

        unsigned pk[8][2];
        #pragma unroll
        for (int mt = 0; mt < 8; ++mt) {
            pk[mt][0] = packbf(acc[mt][0], acc[mt][1]);
            pk[mt][1] = packbf(acc[mt][2], acc[mt][3]);
            acc[mt] = (f4v){0.f, 0.f, 0.f, 0.f};     // reuse for layer 2
        }

        // ---------------- Layer 2: acc = W2'^T @ H1raw^T ----------------
        const int src0 = ((G & 1) << 5) + n16;
        const int src1 = src0 + 16;
        const bool hiG = (G >= 2);
        #pragma unroll
        for (int ks = 0; ks < 4; ++ks) {
            int r00 = __shfl((int)pk[2*ks][0],   src0, 64);
            int r01 = __shfl((int)pk[2*ks][1],   src0, 64);
            int r02 = __shfl((int)pk[2*ks][0],   src1, 64);
            int r03 = __shfl((int)pk[2*ks][1],   src1, 64);
            int r10 = __shfl((int)pk[2*ks+1][0], src0, 64);
            int r11 = __shfl((int)pk[2*ks+1][1], src0, 64);
            int r12 = __shfl((int)pk[2*ks+1][0], src1, 64);
            int r13 = __shfl((int)pk[2*ks+1][1], src1, 64);
            union { int u[4]; s8v v; } hb;
            hb.u[0] = hiG ? r10 : r00; hb.u[1] = hiG ? r11 : r01;
            hb.u[2] = hiG ? r12 : r02; hb.u[3] = hiG ? r13 : r03;
            s8v wfr[8];
            #pragma unroll
            for (int mt = 0; mt < 8; ++mt)
                wfr[mt] = *(const s8v*)&Ws[W2OFF + ((ks*8 + mt)*64 + lane) * 8];
            #pragma unroll
            for (int mt = 0; mt < 8; ++mt)
                acc[mt] = __builtin_amdgcn_mfma_f32_16x16x32_bf16(wfr[mt], hb.v, acc[mt], 0, 0, 0);
        }

        // ---------------- folded LN1 apply + LN2 stats ----------------
        float h2[8][4];
        float sm2 = 0.f, sq2 = 0.f;
        #pragma unroll
        for (int mt = 0; mt < 8; ++mt) {
            const int col = mt*16 + G*4;
            f4v s2l = *(const f4v*)&s2v[col];
            f4v bwl = *(const f4v*)&bwv[col];
            #pragma unroll
            for (int j = 0; j < 4; ++j) {
                float v = rstd1 * (acc[mt][j] - mean1 * s2l[j]) + bwl[j];
                h2[mt][j] = v; sm2 += v; sq2 += v*v;
            }
        }
        sm2 += __shfl_xor(sm2, 16, 64); sm2 += __shfl_xor(sm2, 32, 64);
        sq2 += __shfl_xor(sq2, 16, 64); sq2 += __shfl_xor(sq2, 32, 64);
        const float mean2 = sm2 * (1.f/128.f);
        const float rstd2 = rsqrtf(sq2 * (1.f/128.f) - mean2*mean2 + 1e-5f);

        // ---------------- LN2 + ReLU + (FINE: gather add) + store ----------
        if constexpr (FINE) {
            #pragma unroll
            for (int mt = 0; mt < 8; ++mt) {
                const int col = mt*16 + G*4;
                f4v g2l = *(const f4v*)&g2v[col];
                f4v b2l = *(const f4v*)&b2v[col];
                float z0 = fmaxf((h2[mt][0]-mean2)*rstd2*g2l[0] + b2l[0], 0.f);
                float z1 = fmaxf((h2[mt][1]-mean2)*rstd2*g2l[1] + b2l[1], 0.f);
                float z2 = fmaxf((h2[mt][2]-mean2)*rstd2*g2l[2] + b2l[2], 0.f);
                float z3 = fmaxf((h2[mt][3]-mean2)*rstd2*g2l[3] + b2l[3], 0.f);
                if (hasw) {
                    z0 += bf2f(gv[mt].x); z1 += bf2f(gv[mt].y);
                    z2 += bf2f(gv[mt].z); z3 += bf2f(gv[mt].w);
                }
                float4 o; o.x = z0; o.y = z1; o.z = z2; o.w = z3;
                *(float4*)(outF + (size_t)row * 128 + col) = o;
            }
        } else {
            #pragma unroll
            for (int mt = 0; mt < 8; ++mt) {
                const int col = mt*16 + G*4;
                f4v g2l = *(const f4v*)&g2v[col];
                f4v b2l = *(const f4v*)&b2v[col];
                ushort4 o;
                o.x = (unsigned short)f2bf(fmaxf((h2[mt][0]-mean2)*rstd2*g2l[0] + b2l[0], 0.f));
                o.y = (unsigned short)f2bf(fmaxf((h2[mt][1]-mean2)*rstd2*g2l[1] + b2l[1], 0.f));
                o.z = (unsigned short)f2bf(fmaxf((h2[mt][2]-mean2)*rstd2*g2l[2] + b2l[2], 0.f));
                o.w = (unsigned short)f2bf(fmaxf((h2[mt][3]-mean2)*rstd2*g2l[3] + b2l[3], 0.f));
                *(ushort4*)(outB + (size_t)row * 128 + col) = o;
            }
        }

        wv = wv_next;
    }
}

extern "C" void kernel_launch(void* const* d_in, const int* in_sizes, int n_in,
                              void* d_out, int out_size, void* d_ws, size_t ws_size,
                              hipStream_t stream)
{
    const float* fcoarse = (const float*)d_in[0];
    const float* ffine   = (const float*)d_in[1];
    const float* w1c = (const float*)d_in[2];
    const float* g1c = (const float*)d_in[3];
    const float* b1c = (const float*)d_in[4];
    const float* w2c = (const float*)d_in[5];
    const float* g2c = (const float*)d_in[6];
    const float* b2c = (const float*)d_in[7];
    const float* w1f = (const float*)d_in[8];
    const float* g1f = (const float*)d_in[9];
    const float* b1f = (const float*)d_in[10];
    const float* w2f = (const float*)d_in[11];
    const float* g2f = (const float*)d_in[12];
    const float* b2f = (const float*)d_in[13];
    const int* nrow  = (const int*)d_in[14];
    const int* ncol  = (const int*)d_in[15];

    float* out = (float*)d_out;
    const int Mc = 32768, Mf = 131072;

    // ws: fcB 8MB | winner 512KB | packs 160KB | fold vecs 2KB
    unsigned short* fcB = (unsigned short*)d_ws;
    char* base = (char*)d_ws;
    int*   winner = (int*)(base + 8u*1024*1024);
    short* p1c = (short*)(base + 8u*1024*1024 + 512u*1024);
    short* p2c = p1c + 256*128;
    short* p1f = p2c + 128*128;
    short* p2f = p1f + 128*128;
    float* s2c = (float*)(p2f + 128*128);
    float* bwc = s2c + 128;
    float* s2f = bwc + 128;
    float* bwf = s2f + 128;

    // prep: pack weights + fold vectors + zero winner
    prep_kernel<<<170, 256, 0, stream>>>(w1c, w2c, g1c, b1c, w1f, w2f, g1f, b1f,
                                         p1c, p2c, p1f, p2f, s2c, bwc, s2f, bwf,
                                         winner);

    // coarse MLP (256 blocks x 1 tile of 128 rows) + winner (512 blocks)
    mlp_mfma<256, false, 1><<<512 + Mc/128, 512, 0, stream>>>(
        fcoarse, p1c, p2c, s2c, bwc, g2c, b2c,
        nullptr, fcB, nullptr, nullptr,
        nrow, ncol, winner, 512);

    // fine MLP + fused scatter -> out (512 blocks x 2 tiles of 128 rows)
    mlp_mfma<128, true, 2><<<Mf/256, 512, 0, stream>>>(
        ffine, p1f, p2f, s2f, bwf, g2f, b2f,
        out, nullptr, winner, fcB,
        nullptr, nullptr, nullptr, 0);
}

// Round 14
// 70.263 us; speedup vs baseline: 1.1113x; 1.1113x over previous
//
#include <hip/hip_runtime.h>
#include <hip/hip_bf16.h>

typedef __attribute__((ext_vector_type(8))) short s8v;            // 8 x bf16
typedef __attribute__((ext_vector_type(4))) float f4v;            // 4 x f32

__device__ __forceinline__ short f2bf(float f) {
    __hip_bfloat16 h = __float2bfloat16(f);
    union { __hip_bfloat16 h; short s; } u{h};
    return u.s;
}
__device__ __forceinline__ float bf2f(unsigned short v) {
    union { unsigned u; float f; } x; x.u = ((unsigned)v) << 16; return x.f;
}
__device__ __forceinline__ unsigned packbf(float a, float b) {
    return (unsigned)(unsigned short)f2bf(a) | ((unsigned)(unsigned short)f2bf(b) << 16);
}

// ---------------------------------------------------------------------------
// prep: blocks [0,40) pack weights (W2' = g1 o W2) into MFMA fragment order;
// blocks 40/41 compute LN1-folding vectors s2 = colsum(bf16(W2')), bW2 = b1@W2;
// blocks [42,170) zero the winner array (device-side; hipMemsetAsync cost 40us).
// ---------------------------------------------------------------------------
__global__ void prep_kernel(const float* __restrict__ w1c, const float* __restrict__ w2c,
                            const float* __restrict__ g1c, const float* __restrict__ b1c,
                            const float* __restrict__ w1f, const float* __restrict__ w2f,
                            const float* __restrict__ g1f, const float* __restrict__ b1f,
                            short* __restrict__ p1c, short* __restrict__ p2c,
                            short* __restrict__ p1f, short* __restrict__ p2f,
                            float* __restrict__ s2c, float* __restrict__ bwc,
                            float* __restrict__ s2f, float* __restrict__ bwf,
                            int* __restrict__ win)
{
    int b = blockIdx.x, t = threadIdx.x;
    if (b >= 42) {                        // zero winner: 128 blocks x 256 thr x int4
        int idx4 = (b - 42) * 256 + t;
        int4 z; z.x = 0; z.y = 0; z.z = 0; z.w = 0;
        *(int4*)(win + idx4 * 4) = z;
        return;
    }
    if (b >= 40) {                        // folding vectors
        if (t >= 128) return;
        const float* W  = (b == 40) ? w2c : w2f;
        const float* g1 = (b == 40) ? g1c : g1f;
        const float* b1 = (b == 40) ? b1c : b1f;
        float* s2 = (b == 40) ? s2c : s2f;
        float* bw = (b == 40) ? bwc : bwf;
        float s = 0.f, w2sum = 0.f;
        for (int k = 0; k < 128; ++k) {
            float wv = W[k * 128 + t];
            s     += bf2f((unsigned short)f2bf(g1[k] * wv));  // match MFMA rounding
            w2sum += b1[k] * wv;
        }
        s2[t] = s; bw[t] = w2sum;
        return;
    }
    int id = b * 256 + t;                 // 40*256 = 160 frags * 64 lanes
    int f  = id >> 6, l = id & 63;
    const float* W; const float* g1 = nullptr; short* P; int fl;
    if      (f < 64)  { W = w1c; P = p1c; fl = f; }                   // K=256
    else if (f < 96)  { W = w2c; P = p2c; fl = f - 64;  g1 = g1c; }   // scaled
    else if (f < 128) { W = w1f; P = p1f; fl = f - 96; }
    else              { W = w2f; P = p2f; fl = f - 128; g1 = g1f; }   // scaled
    int g = l >> 4, c = l & 15;
    int ks = fl >> 3, n = fl & 7;
    s8v o;
    #pragma unroll
    for (int e = 0; e < 8; ++e) {
        int k = ks*32 + g*8 + e;
        float v = W[k * 128 + n*16 + c];
        if (g1) v *= g1[k];
        o[e] = f2bf(v);
    }
    *(s8v*)(P + ((fl*64 + l) << 3)) = o;
}

// ---------------------------------------------------------------------------
// COARSE kernel (exact R12 structure, proven): swapped orientation, weights
// LDS-resident with mid-kernel W2' re-stage; winner blocks prefixed.
// ---------------------------------------------------------------------------
__global__ __launch_bounds__(512, 4)
void coarse_mlp(const float* __restrict__ X,
                const short* __restrict__ WpA, const short* __restrict__ WpB,
                const float* __restrict__ s2v, const float* __restrict__ bwv,
                const float* __restrict__ g2v, const float* __restrict__ b2v,
                unsigned short* __restrict__ outB,
                const int* __restrict__ nr, const int* __restrict__ nc,
                int* __restrict__ win, int nWinBlocks)
{
    __shared__ short Ws[32768];                // 64 KB

    if (blockIdx.x < (unsigned)nWinBlocks) {
        int i = blockIdx.x * 512 + threadIdx.x;
        atomicMax(&win[nr[i] * 32 + nc[i]], i + 1);
        return;
    }
    const int bid  = blockIdx.x - nWinBlocks;
    const int tid  = threadIdx.x;
    const int lane = tid & 63;
    const int wave = tid >> 6;
    const int G = lane >> 4, n16 = lane & 15;
    const int row = bid * 128 + wave * 16 + n16;
    const size_t rowK = (size_t)row * 256;

    #pragma unroll
    for (int r = 0; r < 8; ++r) {              // W1: 64KB
        int ch = r*512 + tid;
        *(s8v*)&Ws[ch*8] = *(const s8v*)(WpA + (size_t)ch*8);
    }

    const float* pX = X + rowK + G*8;
    float4 aPf[4][2];
    #pragma unroll
    for (int k2 = 0; k2 < 4; ++k2) {
        aPf[k2][0] = *(const float4*)(pX + k2*32);
        aPf[k2][1] = *(const float4*)(pX + k2*32 + 4);
    }
    __syncthreads();

    f4v acc1[8];
    #pragma unroll
    for (int mt = 0; mt < 8; ++mt) acc1[mt] = (f4v){0.f, 0.f, 0.f, 0.f};

    #pragma unroll
    for (int kb = 0; kb < 8; kb += 4) {
        #pragma unroll
        for (int k2 = 0; k2 < 4; ++k2) {
            const int ks = kb + k2;
            s8v wfr[8];
            #pragma unroll
            for (int mt = 0; mt < 8; ++mt)
                wfr[mt] = *(const s8v*)&Ws[((ks*8 + mt)*64 + lane) * 8];
            s8v xf;
            xf[0] = f2bf(aPf[k2][0].x); xf[1] = f2bf(aPf[k2][0].y);
            xf[2] = f2bf(aPf[k2][0].z); xf[3] = f2bf(aPf[k2][0].w);
            xf[4] = f2bf(aPf[k2][1].x); xf[5] = f2bf(aPf[k2][1].y);
            xf[6] = f2bf(aPf[k2][1].z); xf[7] = f2bf(aPf[k2][1].w);
            #pragma unroll
            for (int mt = 0; mt < 8; ++mt)
                acc1[mt] = __builtin_amdgcn_mfma_f32_16x16x32_bf16(wfr[mt], xf, acc1[mt], 0, 0, 0);
        }
        if (kb + 4 < 8) {
            #pragma unroll
            for (int k2 = 0; k2 < 4; ++k2) {
                aPf[k2][0] = *(const float4*)(pX + (kb+4+k2)*32);
                aPf[k2][1] = *(const float4*)(pX + (kb+4+k2)*32 + 4);
            }
        }
    }

    __syncthreads();
    #pragma unroll
    for (int r = 0; r < 4; ++r) {              // re-stage W2' (32KB)
        int ch = r*512 + tid;
        *(s8v*)&Ws[ch*8] = *(const s8v*)(WpB + (size_t)ch*8);
    }
    __syncthreads();

    float sm = 0.f, sq = 0.f;
    #pragma unroll
    for (int mt = 0; mt < 8; ++mt)
        #pragma unroll
        for (int j = 0; j < 4; ++j) { float v = acc1[mt][j]; sm += v; sq += v*v; }
    sm += __shfl_xor(sm, 16, 64); sm += __shfl_xor(sm, 32, 64);
    sq += __shfl_xor(sq, 16, 64); sq += __shfl_xor(sq, 32, 64);
    const float mean1 = sm * (1.f/128.f);
    const float rstd1 = rsqrtf(sq * (1.f/128.f) - mean1*mean1 + 1e-5f);

    unsigned pk[8][2];
    #pragma unroll
    for (int mt = 0; mt < 8; ++mt) {
        pk[mt][0] = packbf(acc1[mt][0], acc1[mt][1]);
        pk[mt][1] = packbf(acc1[mt][2], acc1[mt][3]);
    }

    f4v acc2[8];
    #pragma unroll
    for (int mt = 0; mt < 8; ++mt) acc2[mt] = (f4v){0.f, 0.f, 0.f, 0.f};

    const int src0 = ((G & 1) << 5) + n16;
    const int src1 = src0 + 16;
    const bool hiG = (G >= 2);
    #pragma unroll
    for (int ks = 0; ks < 4; ++ks) {
        int r00 = __shfl((int)pk[2*ks][0],   src0, 64);
        int r01 = __shfl((int)pk[2*ks][1],   src0, 64);
        int r02 = __shfl((int)pk[2*ks][0],   src1, 64);
        int r03 = __shfl((int)pk[2*ks][1],   src1, 64);
        int r10 = __shfl((int)pk[2*ks+1][0], src0, 64);
        int r11 = __shfl((int)pk[2*ks+1][1], src0, 64);
        int r12 = __shfl((int)pk[2*ks+1][0], src1, 64);
        int r13 = __shfl((int)pk[2*ks+1][1], src1, 64);
        union { int u[4]; s8v v; } hb;
        hb.u[0] = hiG ? r10 : r00; hb.u[1] = hiG ? r11 : r01;
        hb.u[2] = hiG ? r12 : r02; hb.u[3] = hiG ? r13 : r03;
        s8v wfr[8];
        #pragma unroll
        for (int mt = 0; mt < 8; ++mt)
            wfr[mt] = *(const s8v*)&Ws[((ks*8 + mt)*64 + lane) * 8];
        #pragma unroll
        for (int mt = 0; mt < 8; ++mt)
            acc2[mt] = __builtin_amdgcn_mfma_f32_16x16x32_bf16(wfr[mt], hb.v, acc2[mt], 0, 0, 0);
    }

    float h2[8][4];
    float sm2 = 0.f, sq2 = 0.f;
    #pragma unroll
    for (int mt = 0; mt < 8; ++mt) {
        const int col = mt*16 + G*4;
        f4v s2l = *(const f4v*)&s2v[col];
        f4v bwl = *(const f4v*)&bwv[col];
        #pragma unroll
        for (int j = 0; j < 4; ++j) {
            float v = rstd1 * (acc2[mt][j] - mean1 * s2l[j]) + bwl[j];
            h2[mt][j] = v; sm2 += v; sq2 += v*v;
        }
    }
    sm2 += __shfl_xor(sm2, 16, 64); sm2 += __shfl_xor(sm2, 32, 64);
    sq2 += __shfl_xor(sq2, 16, 64); sq2 += __shfl_xor(sq2, 32, 64);
    const float mean2 = sm2 * (1.f/128.f);
    const float rstd2 = rsqrtf(sq2 * (1.f/128.f) - mean2*mean2 + 1e-5f);

    #pragma unroll
    for (int mt = 0; mt < 8; ++mt) {
        const int col = mt*16 + G*4;
        f4v g2l = *(const f4v*)&g2v[col];
        f4v b2l = *(const f4v*)&b2v[col];
        ushort4 o;
        o.x = (unsigned short)f2bf(fmaxf((h2[mt][0]-mean2)*rstd2*g2l[0] + b2l[0], 0.f));
        o.y = (unsigned short)f2bf(fmaxf((h2[mt][1]-mean2)*rstd2*g2l[1] + b2l[1], 0.f));
        o.z = (unsigned short)f2bf(fmaxf((h2[mt][2]-mean2)*rstd2*g2l[2] + b2l[2], 0.f));
        o.w = (unsigned short)f2bf(fmaxf((h2[mt][3]-mean2)*rstd2*g2l[3] + b2l[3], 0.f));
        *(ushort4*)(outB + (size_t)row * 128 + col) = o;
    }
}

// ---------------------------------------------------------------------------
// FINE kernel (R14): R12 core + fully coalesced HBM streams.
// 512 thr, 128 rows/block. LDS: weights 64KB + 16KB bounce = 80KB (2 blk/CU).
// X staged coalesced f32->bf16 in 2 K-halves (granule-XOR swizzle); epilogue
// bounced through the same buffer -> 256B-contiguous out stores (kills the
// 1.46x write amplification from 16-row-scattered float4 stores).
// ---------------------------------------------------------------------------
__global__ __launch_bounds__(512, 4)
void fine_mlp(const float* __restrict__ X,
              const short* __restrict__ WpA, const short* __restrict__ WpB,
              const float* __restrict__ s2v, const float* __restrict__ bwv,
              const float* __restrict__ g2v, const float* __restrict__ b2v,
              float* __restrict__ out,
              const int* __restrict__ winner,
              const unsigned short* __restrict__ fcB)
{
    __shared__ short Ws[32768];     // 64KB: W1 @0 (32KB), W2' @16384 (32KB)
    __shared__ short Xs[8192];      // 16KB: [128 rows][64 bf16] X-half / bounce

    const int tid  = threadIdx.x;
    const int wave = tid >> 6, lane = tid & 63;
    const int G = lane >> 4, n16 = lane & 15;
    const int row0 = blockIdx.x * 128;
    const int rloc = wave * 16 + n16;
    const int row  = row0 + rloc;
    char* xs = (char*)Xs;

    // ---- stage weights (coalesced 16B streams) ----
    #pragma unroll
    for (int r = 0; r < 4; ++r) {
        int ch = r*512 + tid;
        *(s8v*)&Ws[ch*8] = *(const s8v*)(WpA + (size_t)ch*8);
    }
    #pragma unroll
    for (int r = 0; r < 4; ++r) {
        int ch = r*512 + tid;
        *(s8v*)&Ws[16384 + ch*8] = *(const s8v*)(WpB + (size_t)ch*8);
    }

    // ---- stage X K-half 0 (cols 0..63), coalesced, swizzled ----
    #pragma unroll
    for (int it = 0; it < 4; ++it) {
        int i  = it*512 + tid;
        int r  = i >> 4;                     // 16 float4-chunks per row-half
        int c4 = i & 15;
        float4 v = *(const float4*)(X + (size_t)(row0 + r) * 128 + c4*4);
        uint2 p; p.x = packbf(v.x, v.y); p.y = packbf(v.z, v.w);
        int pg = (c4 >> 1) ^ (r & 7);
        *(uint2*)(xs + r*128 + pg*16 + (c4 & 1)*8) = p;
    }
    int wv = winner[row];
    __syncthreads();

    // ---- Layer 1, ks = 0,1 (X-half 0) ----
    f4v acc[8];
    #pragma unroll
    for (int mt = 0; mt < 8; ++mt) acc[mt] = (f4v){0.f, 0.f, 0.f, 0.f};

    #pragma unroll
    for (int ks = 0; ks < 2; ++ks) {
        int pg = (ks*4 + G) ^ (rloc & 7);
        s8v xf = *(const s8v*)(xs + rloc*128 + pg*16);
        s8v wfr[8];
        #pragma unroll
        for (int mt = 0; mt < 8; ++mt)
            wfr[mt] = *(const s8v*)&Ws[((ks*8 + mt)*64 + lane) * 8];
        #pragma unroll
        for (int mt = 0; mt < 8; ++mt)
            acc[mt] = __builtin_amdgcn_mfma_f32_16x16x32_bf16(wfr[mt], xf, acc[mt], 0, 0, 0);
    }
    __syncthreads();

    // ---- stage X K-half 1 (cols 64..127) + gather prefetch ----
    #pragma unroll
    for (int it = 0; it < 4; ++it) {
        int i  = it*512 + tid;
        int r  = i >> 4;
        int c4 = i & 15;
        float4 v = *(const float4*)(X + (size_t)(row0 + r) * 128 + 64 + c4*4);
        uint2 p; p.x = packbf(v.x, v.y); p.y = packbf(v.z, v.w);
        int pg = (c4 >> 1) ^ (r & 7);
        *(uint2*)(xs + r*128 + pg*16 + (c4 & 1)*8) = p;
    }
    // gather prefetch for the epilogue layout (rows it*8+(lane>>3), granule lane&7)
    s8v gv[2][2];
    int wrr[2];
    {
        const int g8 = lane & 7;
        #pragma unroll
        for (int it = 0; it < 2; ++it) {
            int rr = it*8 + (lane >> 3);
            int w  = __shfl(wv, rr, 64);
            wrr[it] = w;
            size_t src = (size_t)((w > 0 ? w - 1 : 0) & 32767) * 128;
            #pragma unroll
            for (int ch = 0; ch < 2; ++ch)
                gv[it][ch] = *(const s8v*)(fcB + src + ch*64 + g8*8);
        }
    }
    __syncthreads();

    // ---- Layer 1, ks = 2,3 (X-half 1) ----
    #pragma unroll
    for (int ks = 2; ks < 4; ++ks) {
        int pg = ((ks-2)*4 + G) ^ (rloc & 7);
        s8v xf = *(const s8v*)(xs + rloc*128 + pg*16);
        s8v wfr[8];
        #pragma unroll
        for (int mt = 0; mt < 8; ++mt)
            wfr[mt] = *(const s8v*)&Ws[((ks*8 + mt)*64 + lane) * 8];
        #pragma unroll
        for (int mt = 0; mt < 8; ++mt)
            acc[mt] = __builtin_amdgcn_mfma_f32_16x16x32_bf16(wfr[mt], xf, acc[mt], 0, 0, 0);
    }

    // ---- LN1 stats ----
    float sm = 0.f, sq = 0.f;
    #pragma unroll
    for (int mt = 0; mt < 8; ++mt)
        #pragma unroll
        for (int j = 0; j < 4; ++j) { float v = acc[mt][j]; sm += v; sq += v*v; }
    sm += __shfl_xor(sm, 16, 64); sm += __shfl_xor(sm, 32, 64);
    sq += __shfl_xor(sq, 16, 64); sq += __shfl_xor(sq, 32, 64);
    const float mean1 = sm * (1.f/128.f);
    const float rstd1 = rsqrtf(sq * (1.f/128.f) - mean1*mean1 + 1e-5f);

    unsigned pk[8][2];
    #pragma unroll
    for (int mt = 0; mt < 8; ++mt) {
        pk[mt][0] = packbf(acc[mt][0], acc[mt][1]);
        pk[mt][1] = packbf(acc[mt][2], acc[mt][3]);
        acc[mt] = (f4v){0.f, 0.f, 0.f, 0.f};       // reuse for layer 2
    }

    // ---- Layer 2 (W2' from LDS; B-frags via shuffles) ----
    const int src0 = ((G & 1) << 5) + n16;
    const int src1 = src0 + 16;
    const bool hiG = (G >= 2);
    #pragma unroll
    for (int ks = 0; ks < 4; ++ks) {
        int r00 = __shfl((int)pk[2*ks][0],   src0, 64);
        int r01 = __shfl((int)pk[2*ks][1],   src0, 64);
        int r02 = __shfl((int)pk[2*ks][0],   src1, 64);
        int r03 = __shfl((int)pk[2*ks][1],   src1, 64);
        int r10 = __shfl((int)pk[2*ks+1][0], src0, 64);
        int r11 = __shfl((int)pk[2*ks+1][1], src0, 64);
        int r12 = __shfl((int)pk[2*ks+1][0], src1, 64);
        int r13 = __shfl((int)pk[2*ks+1][1], src1, 64);
        union { int u[4]; s8v v; } hb;
        hb.u[0] = hiG ? r10 : r00; hb.u[1] = hiG ? r11 : r01;
        hb.u[2] = hiG ? r12 : r02; hb.u[3] = hiG ? r13 : r03;
        s8v wfr[8];
        #pragma unroll
        for (int mt = 0; mt < 8; ++mt)
            wfr[mt] = *(const s8v*)&Ws[16384 + ((ks*8 + mt)*64 + lane) * 8];
        #pragma unroll
        for (int mt = 0; mt < 8; ++mt)
            acc[mt] = __builtin_amdgcn_mfma_f32_16x16x32_bf16(wfr[mt], hb.v, acc[mt], 0, 0, 0);
    }

    // ---- folded LN1 apply + LN2 stats ----
    float h2[8][4];
    float sm2 = 0.f, sq2 = 0.f;
    #pragma unroll
    for (int mt = 0; mt < 8; ++mt) {
        const int col = mt*16 + G*4;
        f4v s2l = *(const f4v*)&s2v[col];
        f4v bwl = *(const f4v*)&bwv[col];
        #pragma unroll
        for (int j = 0; j < 4; ++j) {
            float v = rstd1 * (acc[mt][j] - mean1 * s2l[j]) + bwl[j];
            h2[mt][j] = v; sm2 += v; sq2 += v*v;
        }
    }
    sm2 += __shfl_xor(sm2, 16, 64); sm2 += __shfl_xor(sm2, 32, 64);
    sq2 += __shfl_xor(sq2, 16, 64); sq2 += __shfl_xor(sq2, 32, 64);
    const float mean2 = sm2 * (1.f/128.f);
    const float rstd2 = rsqrtf(sq2 * (1.f/128.f) - mean2*mean2 + 1e-5f);

    // ---- epilogue: per col-half, bounce bf16 via Xs then coalesced store ----
    // (waves touch only their own 16 rows of Xs in both phases: no barrier)
    #pragma unroll
    for (int ch = 0; ch < 2; ++ch) {
        #pragma unroll
        for (int mtL = 0; mtL < 4; ++mtL) {
            const int mt = ch*4 + mtL;
            const int col = mt*16 + G*4;
            f4v g2l = *(const f4v*)&g2v[col];
            f4v b2l = *(const f4v*)&b2v[col];
            float z0 = fmaxf((h2[mt][0]-mean2)*rstd2*g2l[0] + b2l[0], 0.f);
            float z1 = fmaxf((h2[mt][1]-mean2)*rstd2*g2l[1] + b2l[1], 0.f);
            float z2 = fmaxf((h2[mt][2]-mean2)*rstd2*g2l[2] + b2l[2], 0.f);
            float z3 = fmaxf((h2[mt][3]-mean2)*rstd2*g2l[3] + b2l[3], 0.f);
            uint2 p; p.x = packbf(z0, z1); p.y = packbf(z2, z3);
            int pg = (mtL*2 + (G >> 1)) ^ (rloc & 7);
            *(uint2*)(xs + rloc*128 + pg*16 + (G & 1)*8) = p;
        }
        asm volatile("s_waitcnt lgkmcnt(0)" ::: "memory");
        #pragma unroll
        for (int it = 0; it < 2; ++it) {
            const int g8  = lane & 7;
            const int rr  = it*8 + (lane >> 3);
            const int rl2 = wave*16 + rr;
            int pg = g8 ^ (rr & 7);
            s8v v = *(const s8v*)(xs + rl2*128 + pg*16);
            float y[8];
            #pragma unroll
            for (int e = 0; e < 8; ++e) y[e] = bf2f((unsigned short)v[e]);
            if (wrr[it] > 0) {
                #pragma unroll
                for (int e = 0; e < 8; ++e) y[e] += bf2f((unsigned short)gv[it][ch][e]);
            }
            float4 o0 = {y[0], y[1], y[2], y[3]};
            float4 o1 = {y[4], y[5], y[6], y[7]};
            float* op = out + (size_t)(row0 + rl2) * 128 + ch*64 + g8*8;
            *(float4*)op       = o0;
            *(float4*)(op + 4) = o1;
        }
        asm volatile("" ::: "memory");     // keep write/read phases ordered per ch
    }
}

extern "C" void kernel_launch(void* const* d_in, const int* in_sizes, int n_in,
                              void* d_out, int out_size, void* d_ws, size_t ws_size,
                              hipStream_t stream)
{
    const float* fcoarse = (const float*)d_in[0];
    const float* ffine   = (const float*)d_in[1];
    const float* w1c = (const float*)d_in[2];
    const float* g1c = (const float*)d_in[3];
    const float* b1c = (const float*)d_in[4];
    const float* w2c = (const float*)d_in[5];
    const float* g2c = (const float*)d_in[6];
    const float* b2c = (const float*)d_in[7];
    const float* w1f = (const float*)d_in[8];
    const float* g1f = (const float*)d_in[9];
    const float* b1f = (const float*)d_in[10];
    const float* w2f = (const float*)d_in[11];
    const float* g2f = (const float*)d_in[12];
    const float* b2f = (const float*)d_in[13];
    const int* nrow  = (const int*)d_in[14];
    const int* ncol  = (const int*)d_in[15];

    float* out = (float*)d_out;
    const int Mc = 32768, Mf = 131072;

    // ws: fcB 8MB | winner 512KB | packs 160KB | fold vecs 2KB
    unsigned short* fcB = (unsigned short*)d_ws;
    char* base = (char*)d_ws;
    int*   winner = (int*)(base + 8u*1024*1024);
    short* p1c = (short*)(base + 8u*1024*1024 + 512u*1024);
    short* p2c = p1c + 256*128;
    short* p1f = p2c + 128*128;
    short* p2f = p1f + 128*128;
    float* s2c = (float*)(p2f + 128*128);
    float* bwc = s2c + 128;
    float* s2f = bwc + 128;
    float* bwf = s2f + 128;

    // prep: pack weights + fold vectors + zero winner
    prep_kernel<<<170, 256, 0, stream>>>(w1c, w2c, g1c, b1c, w1f, w2f, g1f, b1f,
                                         p1c, p2c, p1f, p2f, s2c, bwc, s2f, bwf,
                                         winner);

    // coarse MLP (256 blocks of 128 rows) + winner resolution (512 blocks)
    coarse_mlp<<<512 + Mc/128, 512, 0, stream>>>(
        fcoarse, p1c, p2c, s2c, bwc, g2c, b2c, fcB,
        nrow, ncol, winner, 512);

    // fine MLP + fused scatter -> out (1024 blocks of 128 rows)
    fine_mlp<<<Mf/128, 512, 0, stream>>>(
        ffine, p1f, p2f, s2f, bwf, g2f, b2f,
        out, winner, fcB);
}